// Round 5
// baseline (1012.577 us; speedup 1.0000x reference)
//
#include <hip/hip_runtime.h>

// Conv2d + BN int8 quantized, MI355X gfx950. Inputs fp32, OUTPUT FP32.
// R2/R3/R4 gave bit-identical absmax across three different compute paths =>
// identical (correct) output streams, systematically mis-compared => the I/O
// contract was wrong: reference output dtype is float32 (doc: "else float*"),
// we were writing bf16 u16 into an fp32 buffer. This round: identical verified
// compute (exact i8 MFMA, in-block layout probe, scalar fallback, no ws), but
// fp32 output writes + input selection by element count.

#define BATCH 32
#define CIN   128
#define HH    56
#define WW    56
#define OCH   256

typedef __attribute__((ext_vector_type(4))) int int4v;

#define AS_ROW 392                       // 3*128 int8 + 8 pad (8B aligned)
#define XS_ROW 136                       // 128 int8 + 8 pad
#define LDS_XS (128 * AS_ROW)            // 50176
#define LDS_SC (LDS_XS + 66 * XS_ROW)    // 59152
#define LDS_AL (LDS_SC + 512)
#define LDS_BI (LDS_AL + 512)
#define LDS_RED (LDS_BI + 512)           // (256 floats)
#define LDS_OK (LDS_RED + 1024)
#define LDS_TOT (LDS_OK + 16)            // 61728 B (<64 KB)

__global__ __launch_bounds__(256) void conv_fused_kernel(
    const float* __restrict__ x, const float* __restrict__ w,
    const float* __restrict__ bias, const float* __restrict__ sxp,
    float* __restrict__ out) {
  __shared__ __attribute__((aligned(16))) char lds[LDS_TOT];
  char* As8 = lds;                         // [128][AS_ROW] int8 weights (kh slab)
  char* Xs8 = lds + LDS_XS;                // [66][XS_ROW] int8 x row
  float* scaleS = (float*)(lds + LDS_SC);  // [128]
  float* alphaS = (float*)(lds + LDS_AL);  // [128]
  float* biasS  = (float*)(lds + LDS_BI);  // [128]
  float* red    = (float*)(lds + LDS_RED); // [256]
  int* okp      = (int*)(lds + LDS_OK);

  const int bi = blockIdx.x;
  const int b  = bi / 56;
  const int oh = bi % 56;
  const int o0 = blockIdx.y * 128;
  const int tid = threadIdx.x;
  const int wave = tid >> 6, lane = tid & 63;
  const int l16 = lane & 15, quad = lane >> 4;
  const float sx = sxp[0];

  if (tid == 0) okp[0] = 1;

  // ---- in-block MFMA layout probe (registers only) ----
  int m_r[4], n_r[4];
  {
    int4v zz = {0, 0, 0, 0};
    long a1 = 0, b1 = 0, a2 = 0, b2 = 0, a3 = 0;
    if (quad == 0) {
      a1 = 1L;                 // A = delta(k=0)
      b1 = (long)(l16 + 1);    // B[0][n] = n+1
      a2 = (long)(l16 + 1);    // A[m][0] = m+1
      b2 = 1L;                 // B = delta(k=0)
    }
    if (quad == 1) a3 |= 1L << 8;    // assumed k=9
    if (quad == 2) a3 |= 1L << 24;   // assumed k=19
    if (quad == 3) a3 |= 1L << 48;   // assumed k=30
    const long b3 = a3;
    int4v d1 = __builtin_amdgcn_mfma_i32_16x16x32_i8(a1, b1, zz, 0, 0, 0);
    int4v d2 = __builtin_amdgcn_mfma_i32_16x16x32_i8(a2, b2, zz, 0, 0, 0);
    int4v d3 = __builtin_amdgcn_mfma_i32_16x16x32_i8(a3, b3, zz, 0, 0, 0);
    bool ok = true;
#pragma unroll
    for (int r = 0; r < 4; ++r) {
      const int v1 = d1[r], v2 = d2[r];
      ok = ok && (v1 >= 1) && (v1 <= 16) && (v2 >= 1) && (v2 <= 16) &&
           (d3[r] == 3);
      n_r[r] = v1 - 1;
      m_r[r] = v2 - 1;
    }
    const unsigned long long bal = __ballot(ok ? 1 : 0);
    if (lane == 0 && bal != ~0ull) okp[0] = 0;
  }

  // ---- per-channel weight scales ----
  {
    const int o = tid >> 1, half = tid & 1;
    const float4* p = (const float4*)(w + (size_t)(o0 + o) * 1152 + half * 576);
    float m = 0.f;
#pragma unroll 4
    for (int i = 0; i < 144; ++i) {
      const float4 v = p[i];
      m = fmaxf(m, fmaxf(fmaxf(fabsf(v.x), fabsf(v.y)),
                         fmaxf(fabsf(v.z), fabsf(v.w))));
    }
    red[tid] = m;
  }
  __syncthreads();
  const int blockok = okp[0];  // block-uniform
  {
    const int o = tid >> 1;
    if ((tid & 1) == 0) {
      const float sc = fmaxf(red[2 * o], red[2 * o + 1]) / 127.0f;  // max/QMAX
      scaleS[o] = sc;
      alphaS[o] = sc * sx;
      biasS[o] = bias[o0 + o];
    }
  }

  int4v acc[2][4];
#pragma unroll
  for (int t = 0; t < 2; ++t)
#pragma unroll
    for (int u = 0; u < 4; ++u) acc[t][u] = (int4v){0, 0, 0, 0};
  int sacc[32];
#pragma unroll
  for (int i = 0; i < 32; ++i) sacc[i] = 0;

  for (int kh = 0; kh < 3; ++kh) {
    const int ih = oh - 1 + kh;
    const bool row_ok = (ih >= 0) && (ih < HH);
    __syncthreads();  // prev slab compute done; scaleS ready (1st iter)
    // stage + quantize x[b][:, ih, -1..64] -> Xs8[iw+1][c]
    for (int idx = tid; idx < 66 * 128; idx += 256) {
      const int col = idx % 66, c = idx / 66, iw = col - 1;
      int q = 0;
      if (row_ok && iw >= 0 && iw < WW) {
        const float xv = x[(((size_t)b * CIN + c) * HH + ih) * WW + iw];
        q = (int)fminf(127.f, fmaxf(-127.f, rintf(xv / sx)));
      }
      Xs8[col * XS_ROW + c] = (char)q;
    }
    // stage + quantize weights for this kh: As8[o][kw*128+c]
    for (int idx = tid; idx < 16384; idx += 256) {
      const int c = idx & 127, o = idx >> 7;
      const float s = scaleS[o];
      const float* wp = w + (size_t)(o0 + o) * 1152 + c * 9 + kh * 3;
#pragma unroll
      for (int kw = 0; kw < 3; ++kw) {
        const int q = (int)fminf(127.f, fmaxf(-127.f, rintf(wp[kw] / s)));
        As8[o * AS_ROW + kw * 128 + c] = (char)q;
      }
    }
    __syncthreads();

    if (blockok) {
      const int obase = wave * 32;
#pragma unroll
      for (int kw = 0; kw < 3; ++kw) {
#pragma unroll
        for (int c0 = 0; c0 < 128; c0 += 32) {
          long aop[2], bop[4];
#pragma unroll
          for (int t = 0; t < 2; ++t)
            aop[t] = *(const long*)(As8 + (obase + t * 16 + l16) * AS_ROW +
                                    kw * 128 + c0 + quad * 8);
#pragma unroll
          for (int u = 0; u < 4; ++u)
            bop[u] = *(const long*)(Xs8 + (u * 16 + l16 + kw) * XS_ROW +
                                    c0 + quad * 8);
#pragma unroll
          for (int t = 0; t < 2; ++t)
#pragma unroll
            for (int u = 0; u < 4; ++u)
              acc[t][u] = __builtin_amdgcn_mfma_i32_16x16x32_i8(
                  aop[t], bop[u], acc[t][u], 0, 0, 0);
        }
      }
    } else {
      const int m = tid >> 1, ow0 = (tid & 1) * 32;
      for (int kw = 0; kw < 3; ++kw) {
        for (int c = 0; c < 128; ++c) {
          const int a = (int)(signed char)As8[m * AS_ROW + kw * 128 + c];
#pragma unroll
          for (int i = 0; i < 32; ++i)
            sacc[i] += a * (int)(signed char)Xs8[(ow0 + i + kw) * XS_ROW + c];
        }
      }
    }
  }

  if (blockok) {
#pragma unroll
    for (int t = 0; t < 2; ++t) {
#pragma unroll
      for (int u = 0; u < 4; ++u) {
#pragma unroll
        for (int r = 0; r < 4; ++r) {
          const int ol = wave * 32 + t * 16 + m_r[r];  // o within 128
          const int ow = u * 16 + n_r[r];
          if (ow < WW) {
            const float v = (float)acc[t][u][r] * alphaS[ol] + biasS[ol];
            out[(((size_t)b * OCH + o0 + ol) * HH + oh) * WW + ow] = v;
          }
        }
      }
    }
  } else {
    const int m = tid >> 1, ow0 = (tid & 1) * 32;
    const float al = alphaS[m], bs = biasS[m];
#pragma unroll
    for (int i = 0; i < 32; ++i) {
      const int ow = ow0 + i;
      if (ow < WW)
        out[(((size_t)b * OCH + o0 + m) * HH + oh) * WW + ow] =
            (float)sacc[i] * al + bs;
    }
  }
}

extern "C" void kernel_launch(void* const* d_in, const int* in_sizes, int n_in,
                              void* d_out, int out_size, void* d_ws, size_t ws_size,
                              hipStream_t stream) {
  // Select inputs by element count (robust to ordering); fall back to position.
  const float *x = nullptr, *w = nullptr, *bias = nullptr, *sx = nullptr;
  for (int i = 0; i < n_in; ++i) {
    const int s = in_sizes[i];
    if (s == BATCH * CIN * HH * WW) x = (const float*)d_in[i];
    else if (s == OCH * CIN * 9)    w = (const float*)d_in[i];
    else if (s == OCH)              bias = (const float*)d_in[i];
    else if (s == 1)                sx = (const float*)d_in[i];
    // lut (65025) ignored: exact integer GEMM done directly
  }
  if (!x || !w || !bias || !sx) {
    x = (const float*)d_in[0]; w = (const float*)d_in[1];
    bias = (const float*)d_in[2]; sx = (const float*)d_in[3];
  }
  float* out = (float*)d_out;  // fp32 output (reference dtype)
  conv_fused_kernel<<<dim3(BATCH * HH, 2), 256, 0, stream>>>(x, w, bias, sx, out);
}

// Round 6
// 360.096 us; speedup vs baseline: 2.8120x; 2.8120x over previous
//
#include <hip/hip_runtime.h>

// Conv2d + BN int8 quantized, MI355X gfx950. Inputs fp32, output fp32.
// R5 passed at 1012 us: VALUBusy 43% / MfmaUtil 3% => cost is the per-block
// re-quantization (528M divides) not the GEMM. This round hoists quantization:
//   quant_w_kernel: per-o scale + int8 pack qw[o][(kh*3+kw)*128+c], alpha[o].
//   quant_x_kernel: int8 pack qxT[b][c4][h][w][4] (dword = 4 channels), coalesced.
//   conv_kernel:    same verified i8-MFMA loop, staging via aligned 8B copies.
// Host falls back to the proven R5 fused kernel if ws_size is too small.

#define BATCH 32
#define CIN   128
#define HH    56
#define WW    56
#define OCH   256

typedef __attribute__((ext_vector_type(4))) int int4v;

#define QX_BYTES (32 * 32 * 56 * 56 * 4)        // 12,845,056
#define QW_BYTES (256 * 1152)                   // 294,912
#define WS_NEEDED (QX_BYTES + QW_BYTES + 1024)

// ---------------- kernel 1: weight quantization ----------------
__global__ __launch_bounds__(256) void quant_w_kernel(
    const float* __restrict__ w, const float* __restrict__ sxp,
    char* __restrict__ qw, float* __restrict__ alpha) {
  __shared__ float red[256];
  __shared__ __attribute__((aligned(8))) char buf[1152];
  const int o = blockIdx.x;
  const int tid = threadIdx.x;
  const float* wrow = w + (size_t)o * 1152;
  float m = 0.f;
  for (int i = tid; i < 288; i += 256) {
    const float4 v = ((const float4*)wrow)[i];
    m = fmaxf(m, fmaxf(fmaxf(fabsf(v.x), fabsf(v.y)),
                       fmaxf(fabsf(v.z), fabsf(v.w))));
  }
  red[tid] = m;
  __syncthreads();
  for (int s = 128; s > 0; s >>= 1) {
    if (tid < s) red[tid] = fmaxf(red[tid], red[tid + s]);
    __syncthreads();
  }
  const float scale = red[0] / 127.0f;  // max/QMAX, fp32, order-independent
  if (tid == 0) alpha[o] = scale * sxp[0];
  for (int i = tid; i < 1152; i += 256) {
    const float q = fminf(127.f, fmaxf(-127.f, rintf(wrow[i] / scale)));
    const int c = i / 9, r = i % 9;  // i = c*9 + kh*3 + kw
    buf[r * 128 + c] = (char)(int)q;
  }
  __syncthreads();
  for (int i = tid; i < 144; i += 256)
    ((long*)(qw + (size_t)o * 1152))[i] = ((const long*)buf)[i];
}

// ---------------- kernel 2: x quantization, channel-packed ----------------
// qxT dword index: (b*32 + c4)*3136 + h*56 + w ; byte k = channel c4*4+k.
__global__ __launch_bounds__(256) void quant_x_kernel(
    const float* __restrict__ x, const float* __restrict__ sxp,
    unsigned int* __restrict__ qx4) {
  const int row = blockIdx.x;  // b*56 + h
  const int b = row / 56, h = row % 56;
  const float sx = sxp[0];
  for (int i = threadIdx.x; i < 1792; i += 256) {
    const int c4 = i / 56, w = i % 56;
    unsigned int pack = 0;
#pragma unroll
    for (int k = 0; k < 4; ++k) {
      const float xv = x[(((size_t)b * 128 + c4 * 4 + k) * 56 + h) * 56 + w];
      const int q = (int)fminf(127.f, fmaxf(-127.f, rintf(xv / sx)));
      pack |= ((unsigned int)(q & 255)) << (8 * k);
    }
    qx4[((size_t)b * 32 + c4) * 3136 + h * 56 + w] = pack;
  }
}

// ---------------- kernel 3: conv (i8 MFMA, pre-quantized operands) --------
#define AS_ROW 392                    // 3*128 int8 + 8 pad (8B aligned)
#define XS_ROW 136                    // 128 int8 + 8 pad
#define LDS_XS (128 * AS_ROW)         // 50176
#define LDS_TOT (LDS_XS + 66 * XS_ROW)

__global__ __launch_bounds__(256) void conv_kernel(
    const unsigned int* __restrict__ qx4, const char* __restrict__ qw,
    const float* __restrict__ alpha, const float* __restrict__ bias,
    float* __restrict__ out) {
  __shared__ __attribute__((aligned(16))) char lds[LDS_TOT];
  char* As8 = lds;             // [128][AS_ROW] int8 weights, one kh slab
  char* Xs8 = lds + LDS_XS;    // [66][XS_ROW] int8 x row (col = iw+1)

  const int bi = blockIdx.x;
  const int b  = bi / 56;
  const int oh = bi % 56;
  const int o0 = blockIdx.y * 128;
  const int tid = threadIdx.x;
  const int wave = tid >> 6, lane = tid & 63;
  const int l16 = lane & 15, quad = lane >> 4;

  // in-block MFMA C/D layout probe (verified working in R5)
  int m_r[4], n_r[4];
  {
    int4v zz = {0, 0, 0, 0};
    long a1 = 0, b1 = 0, a2 = 0, b2 = 0;
    if (quad == 0) {
      a1 = 1L;               // A = delta(k=0)
      b1 = (long)(l16 + 1);  // B[0][n] = n+1
      a2 = (long)(l16 + 1);  // A[m][0] = m+1
      b2 = 1L;               // B = delta(k=0)
    }
    int4v d1 = __builtin_amdgcn_mfma_i32_16x16x32_i8(a1, b1, zz, 0, 0, 0);
    int4v d2 = __builtin_amdgcn_mfma_i32_16x16x32_i8(a2, b2, zz, 0, 0, 0);
#pragma unroll
    for (int r = 0; r < 4; ++r) {
      n_r[r] = (d1[r] - 1) & 15;
      m_r[r] = (d2[r] - 1) & 15;
    }
  }

  int4v acc[2][4];
#pragma unroll
  for (int t = 0; t < 2; ++t)
#pragma unroll
    for (int u = 0; u < 4; ++u) acc[t][u] = (int4v){0, 0, 0, 0};

  for (int kh = 0; kh < 3; ++kh) {
    const int ih = oh - 1 + kh;
    const bool row_ok = (ih >= 0) && (ih < HH);
    __syncthreads();  // previous slab's reads complete before overwrite
    // ---- stage Xs: qxT row -> Xs8[col][c]; pad cols zeroed ----
    if (row_ok) {
      const size_t src0 = ((size_t)b * 32) * 3136 + ih * 56;
      for (int i = tid; i < 1792; i += 256) {      // coalesced 224B per c4
        const int c4 = i / 56, col = i % 56 + 1;   // col = iw+1, iw 0..55
        ((unsigned int*)Xs8)[col * 34 + c4] = qx4[src0 + c4 * 3136 + col - 1];
      }
      for (int i = tid; i < 340; i += 256) {       // zero cols {0, 57..65}
        const int r = i / 34, dw = i % 34;
        const int col = (r == 0) ? 0 : 56 + r;
        ((unsigned int*)Xs8)[col * 34 + dw] = 0u;
      }
    } else {
      for (int i = tid; i < 66 * 34; i += 256) ((unsigned int*)Xs8)[i] = 0u;
    }
    // ---- stage As: qw[o0..+128)[kh][kw][c] -> As8[o][kw*128+c] (8B chunks) --
#pragma unroll
    for (int kws = 0; kws < 3; ++kws) {
      for (int i = tid; i < 2048; i += 256) {
        const int o = i >> 4, j = i & 15;
        *(long*)(As8 + o * AS_ROW + kws * 128 + j * 8) =
            *(const long*)(qw + (size_t)(o0 + o) * 1152 + kh * 384 +
                           kws * 128 + j * 8);
      }
    }
    __syncthreads();

    const int obase = wave * 32;
#pragma unroll
    for (int kw = 0; kw < 3; ++kw) {
#pragma unroll
      for (int c0 = 0; c0 < 128; c0 += 32) {
        long aop[2], bop[4];
#pragma unroll
        for (int t = 0; t < 2; ++t)
          aop[t] = *(const long*)(As8 + (obase + t * 16 + l16) * AS_ROW +
                                  kw * 128 + c0 + quad * 8);
#pragma unroll
        for (int u = 0; u < 4; ++u)
          bop[u] = *(const long*)(Xs8 + (u * 16 + l16 + kw) * XS_ROW +
                                  c0 + quad * 8);
#pragma unroll
        for (int t = 0; t < 2; ++t)
#pragma unroll
          for (int u = 0; u < 4; ++u)
            acc[t][u] = __builtin_amdgcn_mfma_i32_16x16x32_i8(
                aop[t], bop[u], acc[t][u], 0, 0, 0);
      }
    }
  }

#pragma unroll
  for (int t = 0; t < 2; ++t) {
#pragma unroll
    for (int u = 0; u < 4; ++u) {
#pragma unroll
      for (int r = 0; r < 4; ++r) {
        const int ol = wave * 32 + t * 16 + m_r[r];
        const int ow = u * 16 + n_r[r];
        if (ow < WW) {
          const int oo = o0 + ol;
          out[(((size_t)b * OCH + oo) * HH + oh) * WW + ow] =
              (float)acc[t][u][r] * alpha[oo] + bias[oo];
        }
      }
    }
  }
}

// ---------------- fallback: R5's proven fused kernel (ws-free) -------------
#define FAS_ROW 392
#define FXS_ROW 136
#define FLDS_XS (128 * FAS_ROW)
#define FLDS_SC (FLDS_XS + 66 * FXS_ROW)
#define FLDS_AL (FLDS_SC + 512)
#define FLDS_BI (FLDS_AL + 512)
#define FLDS_RED (FLDS_BI + 512)
#define FLDS_TOT (FLDS_RED + 1024)

__global__ __launch_bounds__(256) void conv_fused_kernel(
    const float* __restrict__ x, const float* __restrict__ w,
    const float* __restrict__ bias, const float* __restrict__ sxp,
    float* __restrict__ out) {
  __shared__ __attribute__((aligned(16))) char lds[FLDS_TOT];
  char* As8 = lds;
  char* Xs8 = lds + FLDS_XS;
  float* scaleS = (float*)(lds + FLDS_SC);
  float* alphaS = (float*)(lds + FLDS_AL);
  float* biasS  = (float*)(lds + FLDS_BI);
  float* red    = (float*)(lds + FLDS_RED);

  const int bi = blockIdx.x;
  const int b  = bi / 56;
  const int oh = bi % 56;
  const int o0 = blockIdx.y * 128;
  const int tid = threadIdx.x;
  const int wave = tid >> 6, lane = tid & 63;
  const int l16 = lane & 15, quad = lane >> 4;
  const float sx = sxp[0];

  int m_r[4], n_r[4];
  {
    int4v zz = {0, 0, 0, 0};
    long a1 = 0, b1 = 0, a2 = 0, b2 = 0;
    if (quad == 0) { a1 = 1L; b1 = (long)(l16 + 1); a2 = (long)(l16 + 1); b2 = 1L; }
    int4v d1 = __builtin_amdgcn_mfma_i32_16x16x32_i8(a1, b1, zz, 0, 0, 0);
    int4v d2 = __builtin_amdgcn_mfma_i32_16x16x32_i8(a2, b2, zz, 0, 0, 0);
#pragma unroll
    for (int r = 0; r < 4; ++r) { n_r[r] = (d1[r] - 1) & 15; m_r[r] = (d2[r] - 1) & 15; }
  }
  {
    const int o = tid >> 1, half = tid & 1;
    const float4* p = (const float4*)(w + (size_t)(o0 + o) * 1152 + half * 576);
    float m = 0.f;
#pragma unroll 4
    for (int i = 0; i < 144; ++i) {
      const float4 v = p[i];
      m = fmaxf(m, fmaxf(fmaxf(fabsf(v.x), fabsf(v.y)), fmaxf(fabsf(v.z), fabsf(v.w))));
    }
    red[tid] = m;
  }
  __syncthreads();
  {
    const int o = tid >> 1;
    if ((tid & 1) == 0) {
      const float sc = fmaxf(red[2 * o], red[2 * o + 1]) / 127.0f;
      scaleS[o] = sc; alphaS[o] = sc * sx; biasS[o] = bias[o0 + o];
    }
  }
  int4v acc[2][4];
#pragma unroll
  for (int t = 0; t < 2; ++t)
#pragma unroll
    for (int u = 0; u < 4; ++u) acc[t][u] = (int4v){0, 0, 0, 0};

  for (int kh = 0; kh < 3; ++kh) {
    const int ih = oh - 1 + kh;
    const bool row_ok = (ih >= 0) && (ih < HH);
    __syncthreads();
    for (int idx = tid; idx < 66 * 128; idx += 256) {
      const int col = idx % 66, c = idx / 66, iw = col - 1;
      int q = 0;
      if (row_ok && iw >= 0 && iw < WW) {
        const float xv = x[(((size_t)b * CIN + c) * HH + ih) * WW + iw];
        q = (int)fminf(127.f, fmaxf(-127.f, rintf(xv / sx)));
      }
      Xs8[col * FXS_ROW + c] = (char)q;
    }
    for (int idx = tid; idx < 16384; idx += 256) {
      const int c = idx & 127, o = idx >> 7;
      const float s = scaleS[o];
      const float* wp = w + (size_t)(o0 + o) * 1152 + c * 9 + kh * 3;
#pragma unroll
      for (int kw = 0; kw < 3; ++kw) {
        const int q = (int)fminf(127.f, fmaxf(-127.f, rintf(wp[kw] / s)));
        As8[o * FAS_ROW + kw * 128 + c] = (char)q;
      }
    }
    __syncthreads();
    const int obase = wave * 32;
#pragma unroll
    for (int kw = 0; kw < 3; ++kw) {
#pragma unroll
      for (int c0 = 0; c0 < 128; c0 += 32) {
        long aop[2], bop[4];
#pragma unroll
        for (int t = 0; t < 2; ++t)
          aop[t] = *(const long*)(As8 + (obase + t * 16 + l16) * FAS_ROW + kw * 128 + c0 + quad * 8);
#pragma unroll
        for (int u = 0; u < 4; ++u)
          bop[u] = *(const long*)(Xs8 + (u * 16 + l16 + kw) * FXS_ROW + c0 + quad * 8);
#pragma unroll
        for (int t = 0; t < 2; ++t)
#pragma unroll
          for (int u = 0; u < 4; ++u)
            acc[t][u] = __builtin_amdgcn_mfma_i32_16x16x32_i8(aop[t], bop[u], acc[t][u], 0, 0, 0);
      }
    }
  }
#pragma unroll
  for (int t = 0; t < 2; ++t) {
#pragma unroll
    for (int u = 0; u < 4; ++u) {
#pragma unroll
      for (int r = 0; r < 4; ++r) {
        const int ol = wave * 32 + t * 16 + m_r[r];
        const int ow = u * 16 + n_r[r];
        if (ow < WW)
          out[(((size_t)b * OCH + o0 + ol) * HH + oh) * WW + ow] =
              (float)acc[t][u][r] * alphaS[ol] + biasS[ol];
      }
    }
  }
}

extern "C" void kernel_launch(void* const* d_in, const int* in_sizes, int n_in,
                              void* d_out, int out_size, void* d_ws, size_t ws_size,
                              hipStream_t stream) {
  const float *x = nullptr, *w = nullptr, *bias = nullptr, *sx = nullptr;
  for (int i = 0; i < n_in; ++i) {
    const int s = in_sizes[i];
    if (s == BATCH * CIN * HH * WW) x = (const float*)d_in[i];
    else if (s == OCH * CIN * 9)    w = (const float*)d_in[i];
    else if (s == OCH)              bias = (const float*)d_in[i];
    else if (s == 1)                sx = (const float*)d_in[i];
  }
  if (!x || !w || !bias || !sx) {
    x = (const float*)d_in[0]; w = (const float*)d_in[1];
    bias = (const float*)d_in[2]; sx = (const float*)d_in[3];
  }
  float* out = (float*)d_out;

  if (ws_size >= (size_t)WS_NEEDED) {
    unsigned int* qx4 = (unsigned int*)d_ws;
    char* qw = (char*)d_ws + QX_BYTES;
    float* alpha = (float*)((char*)d_ws + QX_BYTES + QW_BYTES);
    quant_w_kernel<<<OCH, 256, 0, stream>>>(w, sx, qw, alpha);
    quant_x_kernel<<<BATCH * HH, 256, 0, stream>>>(x, sx, qx4);
    conv_kernel<<<dim3(BATCH * HH, 2), 256, 0, stream>>>(qx4, qw, alpha, bias, out);
  } else {
    conv_fused_kernel<<<dim3(BATCH * HH, 2), 256, 0, stream>>>(x, w, bias, sx, out);
  }
}